// Round 6
// baseline (169.714 us; speedup 1.0000x reference)
//
#include <hip/hip_runtime.h>
#include <hip/hip_bf16.h>

#define N_TOKENS 8192
#define IN_FEAT 1024
#define OUT_FEAT 1024
#define NUM_EXPERT 8

#define BM 128
#define BN 128
#define BK 32
#define MAXT 71   // max active m-tiles: 64 + (8-1)

typedef __bf16 bf16x8 __attribute__((ext_vector_type(8)));
typedef float f32x4 __attribute__((ext_vector_type(4)));

// fp32 -> bf16 round-to-nearest-even, two packed into one dword.
__device__ __forceinline__ unsigned int rne16(float x) {
    union { float f; unsigned int u; } c;
    c.f = x;
    unsigned int u = c.u;
    u += 0x7fffu + ((u >> 16) & 1u);
    return u >> 16;
}
__device__ __forceinline__ unsigned int pk2(float x, float y) {
    return rne16(x) | (rne16(y) << 16);
}

// async global->LDS, 16 B per lane; LDS dest is wave-uniform base + lane*16.
__device__ __forceinline__ void load_lds16(const void* g, void* l) {
    __builtin_amdgcn_global_load_lds(
        (const __attribute__((address_space(1))) unsigned int*)g,
        (__attribute__((address_space(3))) unsigned int*)l,
        16, 0, 0);
}

// ---- sort: histogram -> scan(+tile table) -> scatter ----

__global__ __launch_bounds__(256) void moe_hist(const int* __restrict__ gate,
                                                int* __restrict__ cnt) {
    __shared__ int lc[NUM_EXPERT];
    const int t = threadIdx.x;
    if (t < NUM_EXPERT) lc[t] = 0;
    __syncthreads();
    int g = gate[blockIdx.x * 256 + t];
    atomicAdd(&lc[g], 1);
    __syncthreads();
    if (t < NUM_EXPERT) atomicAdd(&cnt[t], lc[t]);
}

// tiles[i] = tbase(0:12) | e(13:15) | rows(16:23); *ntiles = count
__global__ void moe_scan(const int* __restrict__ cnt, int* __restrict__ seg,
                         int* __restrict__ cur, int* __restrict__ tiles,
                         int* __restrict__ ntiles) {
    int s = 0;
    #pragma unroll
    for (int e = 0; e < NUM_EXPERT; ++e) { seg[e] = s; cur[e] = s; s += cnt[e]; }
    seg[NUM_EXPERT] = s;
    int T = 0;
    for (int e = 0; e < NUM_EXPERT; ++e) {
        int c = cnt[e], b = seg[e];
        for (int mt = 0; mt * BM < c; ++mt) {
            int rows = c - mt * BM; if (rows > BM) rows = BM;
            tiles[T++] = (b + mt * BM) | (e << 13) | (rows << 16);
        }
    }
    *ntiles = T;
}

__global__ __launch_bounds__(256) void moe_scatter(const int* __restrict__ gate,
                                                   int* __restrict__ cur,
                                                   int* __restrict__ perm) {
    const int t = threadIdx.x;
    const int lane = t & 63;
    const unsigned long long lt = (lane == 0) ? 0ull : (~0ull >> (64 - lane));
    const int i = blockIdx.x * 256 + t;
    int g = gate[i];
    #pragma unroll
    for (int e = 0; e < NUM_EXPERT; ++e) {
        unsigned long long m = __ballot(g == e);
        if (g == e) {
            int rank = __popcll(m & lt);
            int leader = (int)__ffsll((unsigned long long)m) - 1;
            int p0 = 0;
            if (rank == 0) p0 = atomicAdd(&cur[e], __popcll(m));
            p0 = __shfl(p0, leader);
            perm[p0 + rank] = i;
        }
    }
}

// ---- prep: bf16 convert; A gathered in perm order (A2[r] = inp[perm[r]]) ----
__global__ __launch_bounds__(256) void moe_prep(const float* __restrict__ inp,
                                                const float* __restrict__ weight,
                                                const int* __restrict__ perm,
                                                unsigned int* __restrict__ A2,
                                                unsigned int* __restrict__ W2) {
    const int bid = blockIdx.x;
    const int t = threadIdx.x;
    const int wave = t >> 6, lane = t & 63;
    const float* src;
    unsigned int* dst;
    if (bid < 2048) {
        int row = bid * 4 + wave;
        src = inp + perm[row] * IN_FEAT;
        dst = A2 + row * (IN_FEAT / 2);
    } else {
        int row = (bid - 2048) * 4 + wave;
        src = weight + row * IN_FEAT;
        dst = W2 + row * (IN_FEAT / 2);
    }
    #pragma unroll
    for (int j = 0; j < 4; ++j) {
        float4 v = *(const float4*)(src + j * 256 + lane * 4);
        uint2 o;
        o.x = pk2(v.x, v.y);
        o.y = pk2(v.z, v.w);
        *(uint2*)(dst + j * 128 + lane * 2) = o;
    }
}

// ---- bf16 grouped GEMM: 4-stage LDS ring, manual vmcnt + raw barrier ----
// Invariant: 12 DMAs outstanding per wave at stage top; vmcnt(8) retires the
// arriving stage; raw s_barrier publishes it without draining the 2 in flight.
__global__ __launch_bounds__(256, 2) void moe_gemm(
    const unsigned short* __restrict__ A2,   // bf16 [8192][1024], perm order
    const unsigned short* __restrict__ W2,   // bf16 [8][1024][1024]
    const int* __restrict__ perm,
    const int* __restrict__ tiles,
    const int* __restrict__ ntiles,
    float* __restrict__ out) {

    const int bid = blockIdx.x;
    const int tIdx = bid >> 3;
    const int ntile = bid & 7;
    if (tIdx >= *ntiles) return;
    const int tile = tiles[tIdx];
    const int tbase = tile & 8191;
    const int e = (tile >> 13) & 7;
    const int rows = tile >> 16;

    __shared__ __align__(16) unsigned short lA[4][BM * BK];  // 4 x 8 KB
    __shared__ __align__(16) unsigned short lB[4][BN * BK];  // 4 x 8 KB  (total 64 KB)

    const int t = threadIdx.x;

    // staging: chunk c in {t, t+256}: row = c>>2, k-part p = (c&3)^(row&3)
    const int crow = t >> 2;                 // 0..63
    const int p = (t & 3) ^ (crow & 3);
    int ar0 = tbase + crow;       if (ar0 > N_TOKENS - 1) ar0 = N_TOKENS - 1;
    int ar1 = tbase + 64 + crow;  if (ar1 > N_TOKENS - 1) ar1 = N_TOKENS - 1;
    const unsigned short* gA0 = A2 + ar0 * IN_FEAT + p * 8;
    const unsigned short* gA1 = A2 + ar1 * IN_FEAT + p * 8;
    const unsigned short* gB0 = W2 + e * (OUT_FEAT * IN_FEAT)
                                + (ntile * BN + crow) * IN_FEAT + p * 8;
    const unsigned short* gB1 = gB0 + 64 * IN_FEAT;
    const int dofs = t * 8;                  // chunk t
    const int dofs2 = (t + 256) * 8;         // chunk t+256

    // fragment read addresses (swizzle-matched)
    const int wave = t >> 6;
    const int lane = t & 63;
    const int wm = (wave & 1) << 6;
    const int wn = (wave >> 1) << 6;
    const int l15 = lane & 15;
    const int quad = lane >> 4;
    const int qx = quad ^ (l15 & 3);
    const int fofsA = (wm + l15) * BK + qx * 8;
    const int fofsB = (wn + l15) * BK + qx * 8;

    f32x4 acc[4][4];
    #pragma unroll
    for (int i = 0; i < 4; ++i)
        #pragma unroll
        for (int j = 0; j < 4; ++j)
            acc[i][j] = (f32x4)0.0f;

#define ISSUE(sidx, buf) do {                                          \
        int _s = (sidx) > 31 ? 31 : (sidx);                            \
        load_lds16(gA0 + _s * BK, &lA[buf][dofs]);                     \
        load_lds16(gA1 + _s * BK, &lA[buf][dofs2]);                    \
        load_lds16(gB0 + _s * BK, &lB[buf][dofs]);                     \
        load_lds16(gB1 + _s * BK, &lB[buf][dofs2]);                    \
    } while (0)

    // prologue: stages 0,1,2 -> bufs 0,1,2 (12 DMAs outstanding per wave)
    ISSUE(0, 0);
    ISSUE(1, 1);
    ISSUE(2, 2);

#define STAGE(b) {                                                     \
        const int s = ss * 4 + (b);                                    \
        asm volatile("s_waitcnt vmcnt(8)" ::: "memory");               \
        __builtin_amdgcn_s_barrier();                                  \
        asm volatile("" ::: "memory");                                 \
        ISSUE(s + 3, ((b) + 3) & 3);                                   \
        bf16x8 af[4], bq[4];                                           \
        _Pragma("unroll")                                              \
        for (int i = 0; i < 4; ++i)                                    \
            af[i] = *(const bf16x8*)&lA[b][fofsA + i * 16 * BK];       \
        _Pragma("unroll")                                              \
        for (int j = 0; j < 4; ++j)                                    \
            bq[j] = *(const bf16x8*)&lB[b][fofsB + j * 16 * BK];       \
        _Pragma("unroll")                                              \
        for (int i = 0; i < 4; ++i)                                    \
            _Pragma("unroll")                                          \
            for (int j = 0; j < 4; ++j)                                \
                acc[i][j] = __builtin_amdgcn_mfma_f32_16x16x32_bf16(   \
                    af[i], bq[j], acc[i][j], 0, 0, 0);                 \
    }

    #pragma unroll 1
    for (int ss = 0; ss < 8; ++ss) {
        STAGE(0)
        STAGE(1)
        STAGE(2)
        STAGE(3)
    }
#undef STAGE
#undef ISSUE

    // epilogue: C/D layout col=lane&15, row=quad*4+reg
    #pragma unroll
    for (int mi = 0; mi < 4; ++mi) {
        #pragma unroll
        for (int r = 0; r < 4; ++r) {
            int row = wm + mi * 16 + quad * 4 + r;
            if (row < rows) {
                int token = perm[tbase + row];
                float* op = out + token * OUT_FEAT + ntile * BN + wn;
                #pragma unroll
                for (int ni = 0; ni < 4; ++ni)
                    op[ni * 16 + l15] = acc[mi][ni][r];
            }
        }
    }
}

// ---- fallback (fused-convert gemm) if ws can't hold bf16 copies ----
#define FLDSW 20
__global__ __launch_bounds__(256, 4) void moe_gemm_fb(
    const float* __restrict__ inp,
    const float* __restrict__ weight,
    const int* __restrict__ perm,
    const int* __restrict__ seg,
    float* __restrict__ out) {

    const int bid = blockIdx.x;
    const int mtile = bid >> 7;
    const int e = (bid >> 4) & 7;
    const int ntile = bid & 15;

    const int base = seg[e];
    const int cnt = seg[e + 1] - base;
    if (mtile * 128 >= cnt) return;

    __shared__ unsigned int lA[128 * FLDSW];
    __shared__ unsigned int lB[64 * FLDSW];
    __shared__ int rowids[128];

    const int t = threadIdx.x;
    if (t < 128) {
        int r = mtile * 128 + t;
        rowids[t] = (r < cnt) ? perm[base + r] : -1;
    }
    __syncthreads();

    const int srow = t >> 1;
    const int scol = (t & 1) << 4;
    const int tokA = rowids[srow];
    const bool aval = (tokA >= 0);
    const float* aptr = inp + (aval ? tokA : 0) * IN_FEAT + scol;
    const int sdstA = srow * FLDSW + (scol >> 1);
    const int browB = t >> 2;
    const int bcol = (t & 3) << 3;
    const float* bptr = weight + e * (OUT_FEAT * IN_FEAT)
                        + (ntile * 64 + browB) * IN_FEAT + bcol;
    const int sdstB = browB * FLDSW + (bcol >> 1);

    const int wave = t >> 6;
    const int lane = t & 63;
    const int wm = (wave & 1) << 6;
    const int wn = (wave >> 1) << 5;
    const int l15 = lane & 15;
    const int quad = lane >> 4;

    f32x4 acc[4][2];
    #pragma unroll
    for (int i = 0; i < 4; ++i)
        #pragma unroll
        for (int j = 0; j < 2; ++j)
            acc[i][j] = (f32x4)0.0f;

    float4 ra[4], rb[2];
    {
        const float4* ap = (const float4*)aptr;
        const float4* bp = (const float4*)bptr;
        #pragma unroll
        for (int i = 0; i < 4; ++i) ra[i] = ap[i];
        #pragma unroll
        for (int i = 0; i < 2; ++i) rb[i] = bp[i];
    }

    for (int k0 = 0; k0 < IN_FEAT; k0 += 32) {
        unsigned int ua[8], ub[4];
        #pragma unroll
        for (int i = 0; i < 4; ++i) {
            ua[2 * i]     = pk2(ra[i].x, ra[i].y);
            ua[2 * i + 1] = pk2(ra[i].z, ra[i].w);
        }
        #pragma unroll
        for (int i = 0; i < 2; ++i) {
            ub[2 * i]     = pk2(rb[i].x, rb[i].y);
            ub[2 * i + 1] = pk2(rb[i].z, rb[i].w);
        }
        if (!aval) {
            #pragma unroll
            for (int i = 0; i < 8; ++i) ua[i] = 0u;
        }

        __syncthreads();
        *(uint4*)&lA[sdstA]     = make_uint4(ua[0], ua[1], ua[2], ua[3]);
        *(uint4*)&lA[sdstA + 4] = make_uint4(ua[4], ua[5], ua[6], ua[7]);
        *(uint4*)&lB[sdstB]     = make_uint4(ub[0], ub[1], ub[2], ub[3]);
        __syncthreads();

        if (k0 + 32 < IN_FEAT) {
            const float4* ap = (const float4*)(aptr + k0 + 32);
            const float4* bp = (const float4*)(bptr + k0 + 32);
            #pragma unroll
            for (int i = 0; i < 4; ++i) ra[i] = ap[i];
            #pragma unroll
            for (int i = 0; i < 2; ++i) rb[i] = bp[i];
        }

        bf16x8 af[4], bq[2];
        #pragma unroll
        for (int i = 0; i < 4; ++i)
            af[i] = *(const bf16x8*)&lA[(wm + i * 16 + l15) * FLDSW + (quad << 2)];
        #pragma unroll
        for (int j = 0; j < 2; ++j)
            bq[j] = *(const bf16x8*)&lB[(wn + j * 16 + l15) * FLDSW + (quad << 2)];

        #pragma unroll
        for (int i = 0; i < 4; ++i)
            #pragma unroll
            for (int j = 0; j < 2; ++j)
                acc[i][j] = __builtin_amdgcn_mfma_f32_16x16x32_bf16(
                    af[i], bq[j], acc[i][j], 0, 0, 0);
    }

    #pragma unroll
    for (int mi = 0; mi < 4; ++mi) {
        #pragma unroll
        for (int r = 0; r < 4; ++r) {
            int row = wm + mi * 16 + quad * 4 + r;
            int token = rowids[row];
            if (token >= 0) {
                float* op = out + token * OUT_FEAT + ntile * 64 + wn;
                #pragma unroll
                for (int ni = 0; ni < 2; ++ni)
                    op[ni * 16 + l15] = acc[mi][ni][r];
            }
        }
    }
}

extern "C" void kernel_launch(void* const* d_in, const int* in_sizes, int n_in,
                              void* d_out, int out_size, void* d_ws, size_t ws_size,
                              hipStream_t stream) {
    const float* inp = (const float*)d_in[0];
    const int* gate = (const int*)d_in[1];
    const float* weight = (const float*)d_in[2];
    float* out = (float*)d_out;

    int* perm = (int*)d_ws;           // 8192 ints
    int* seg = perm + N_TOKENS;       // 9 (pad 16)
    int* cnt = seg + 16;              // 8
    int* cur = cnt + 8;               // 8
    int* tiles = cur + 8;             // MAXT+1
    int* ntiles = tiles + 96;         // 1

    hipMemsetAsync(cnt, 0, 16 * sizeof(int), stream);
    moe_hist<<<N_TOKENS / 256, 256, 0, stream>>>(gate, cnt);
    moe_scan<<<1, 1, 0, stream>>>(cnt, seg, cur, tiles, ntiles);
    moe_scatter<<<N_TOKENS / 256, 256, 0, stream>>>(gate, cur, perm);

    const size_t need = 65536 + 2ull * N_TOKENS * IN_FEAT * 2;  // 33.6 MB
    if (ws_size >= need) {
        unsigned int* A2 = (unsigned int*)((char*)d_ws + 65536);
        unsigned int* W2 = A2 + (N_TOKENS * IN_FEAT / 2);
        moe_prep<<<4096, 256, 0, stream>>>(inp, weight, perm, A2, W2);
        moe_gemm<<<MAXT * 8, 256, 0, stream>>>((const unsigned short*)A2,
                                               (const unsigned short*)W2,
                                               perm, tiles, ntiles, out);
    } else {
        moe_gemm_fb<<<8192, 256, 0, stream>>>(inp, weight, perm, seg, out);
    }
}

// Round 7
// 153.149 us; speedup vs baseline: 1.1082x; 1.1082x over previous
//
#include <hip/hip_runtime.h>
#include <hip/hip_bf16.h>

#define N_TOKENS 8192
#define IN_FEAT 1024
#define OUT_FEAT 1024
#define NUM_EXPERT 8

#define BM 128
#define BN 128
#define BK 32

typedef __bf16 bf16x8 __attribute__((ext_vector_type(8)));
typedef float f32x4 __attribute__((ext_vector_type(4)));

// fp32 -> bf16 round-to-nearest-even, two packed into one dword.
__device__ __forceinline__ unsigned int rne16(float x) {
    union { float f; unsigned int u; } c;
    c.f = x;
    unsigned int u = c.u;
    u += 0x7fffu + ((u >> 16) & 1u);
    return u >> 16;
}
__device__ __forceinline__ unsigned int pk2(float x, float y) {
    return rne16(x) | (rne16(y) << 16);
}

// async global->LDS, 16 B per lane; LDS dest is wave-uniform base + lane*16.
__device__ __forceinline__ void load_lds16(const void* g, void* l) {
    __builtin_amdgcn_global_load_lds(
        (const __attribute__((address_space(1))) unsigned int*)g,
        (__attribute__((address_space(3))) unsigned int*)l,
        16, 0, 0);
}

// ---- sort: histogram -> scan -> scatter ----

__global__ __launch_bounds__(256) void moe_hist(const int* __restrict__ gate,
                                                int* __restrict__ cnt) {
    __shared__ int lc[NUM_EXPERT];
    const int t = threadIdx.x;
    if (t < NUM_EXPERT) lc[t] = 0;
    __syncthreads();
    int g = gate[blockIdx.x * 256 + t];
    atomicAdd(&lc[g], 1);
    __syncthreads();
    if (t < NUM_EXPERT) atomicAdd(&cnt[t], lc[t]);
}

__global__ void moe_scan(const int* __restrict__ cnt, int* __restrict__ seg,
                         int* __restrict__ cur) {
    int s = 0;
    #pragma unroll
    for (int e = 0; e < NUM_EXPERT; ++e) { seg[e] = s; cur[e] = s; s += cnt[e]; }
    seg[NUM_EXPERT] = s;
}

__global__ __launch_bounds__(256) void moe_scatter(const int* __restrict__ gate,
                                                   int* __restrict__ cur,
                                                   int* __restrict__ perm) {
    const int t = threadIdx.x;
    const int lane = t & 63;
    const unsigned long long lt = (lane == 0) ? 0ull : (~0ull >> (64 - lane));
    const int i = blockIdx.x * 256 + t;
    int g = gate[i];
    #pragma unroll
    for (int e = 0; e < NUM_EXPERT; ++e) {
        unsigned long long m = __ballot(g == e);
        if (g == e) {
            int rank = __popcll(m & lt);
            int leader = (int)__ffsll((unsigned long long)m) - 1;
            int p0 = 0;
            if (rank == 0) p0 = atomicAdd(&cur[e], __popcll(m));
            p0 = __shfl(p0, leader);
            perm[p0 + rank] = i;
        }
    }
}

// ---- prep: bf16 convert; A gathered in perm order (A2[r] = inp[perm[r]]) ----
__global__ __launch_bounds__(256) void moe_prep(const float* __restrict__ inp,
                                                const float* __restrict__ weight,
                                                const int* __restrict__ perm,
                                                unsigned int* __restrict__ A2,
                                                unsigned int* __restrict__ W2) {
    const int bid = blockIdx.x;
    const int t = threadIdx.x;
    const int wave = t >> 6, lane = t & 63;
    const float* src;
    unsigned int* dst;
    if (bid < 2048) {
        int row = bid * 4 + wave;
        src = inp + perm[row] * IN_FEAT;
        dst = A2 + row * (IN_FEAT / 2);
    } else {
        int row = (bid - 2048) * 4 + wave;
        src = weight + row * IN_FEAT;
        dst = W2 + row * (IN_FEAT / 2);
    }
    #pragma unroll
    for (int j = 0; j < 4; ++j) {
        float4 v = *(const float4*)(src + j * 256 + lane * 4);
        uint2 o;
        o.x = pk2(v.x, v.y);
        o.y = pk2(v.z, v.w);
        *(uint2*)(dst + j * 128 + lane * 2) = o;
    }
}

// ---- bf16 grouped GEMM: dbuf DMA pipeline, 128x128, BK=32.
// bid = mtile*64 + ntile*8 + e  =>  bid%8 = e pins each expert's blocks (and
// every A-tile's 8 ntile-sharers) to one XCD: 2 MB of W2 + live A-tiles stay
// L2-resident. Low-mtile bids are active for all experts -> dense dispatch.
__global__ __launch_bounds__(256, 4) void moe_gemm(
    const unsigned short* __restrict__ A2,   // bf16 [8192][1024], perm order
    const unsigned short* __restrict__ W2,   // bf16 [8][1024][1024]
    const int* __restrict__ perm,
    const int* __restrict__ seg,
    float* __restrict__ out) {

    const int bid = blockIdx.x;
    const int e = bid & 7;
    const int ntile = (bid >> 3) & 7;
    const int mtile = bid >> 6;

    const int base = seg[e];
    const int cnt = seg[e + 1] - base;
    if (mtile * BM >= cnt) return;
    const int tbase = base + mtile * BM;
    int rows = cnt - mtile * BM; if (rows > BM) rows = BM;

    __shared__ __align__(16) unsigned short lA[2][BM * BK];   // 2 x 8 KB
    __shared__ __align__(16) unsigned short lB[2][BN * BK];   // 2 x 8 KB

    const int t = threadIdx.x;

    // staging: chunk c in {t, t+256}: row = c>>2, k-part p = (c&3)^(row&3)
    const int crow = t >> 2;                 // 0..63
    const int p = (t & 3) ^ (crow & 3);
    int ar0 = tbase + crow;       if (ar0 > N_TOKENS - 1) ar0 = N_TOKENS - 1;
    int ar1 = tbase + 64 + crow;  if (ar1 > N_TOKENS - 1) ar1 = N_TOKENS - 1;
    const unsigned short* gA0 = A2 + ar0 * IN_FEAT + p * 8;
    const unsigned short* gA1 = A2 + ar1 * IN_FEAT + p * 8;
    const unsigned short* gB0 = W2 + e * (OUT_FEAT * IN_FEAT)
                                + (ntile * BN + crow) * IN_FEAT + p * 8;
    const unsigned short* gB1 = gB0 + 64 * IN_FEAT;
    const int dofs = t * 8;                  // chunk t
    const int dofs2 = (t + 256) * 8;         // chunk t+256

    // fragment read addresses (swizzle-matched)
    const int wave = t >> 6;
    const int lane = t & 63;
    const int wm = (wave & 1) << 6;
    const int wn = (wave >> 1) << 6;
    const int l15 = lane & 15;
    const int quad = lane >> 4;
    const int qx = quad ^ (l15 & 3);
    const int fofsA = (wm + l15) * BK + qx * 8;
    const int fofsB = (wn + l15) * BK + qx * 8;

    f32x4 acc[4][4];
    #pragma unroll
    for (int i = 0; i < 4; ++i)
        #pragma unroll
        for (int j = 0; j < 4; ++j)
            acc[i][j] = (f32x4)0.0f;

    // prologue: slab 0 -> buf0
    load_lds16(gA0, &lA[0][dofs]);
    load_lds16(gA1, &lA[0][dofs2]);
    load_lds16(gB0, &lB[0][dofs]);
    load_lds16(gB1, &lB[0][dofs2]);

    #pragma unroll 1
    for (int kk = 0; kk < 16; ++kk) {
        const int k0 = kk * 64;  // shorts; slab 2kk at k0, slab 2kk+1 at k0+32

        __syncthreads();  // drain DMA(2kk) + prev reads
        // issue slab 2kk+1 -> buf1 (overlaps compute of slab 2kk)
        load_lds16(gA0 + k0 + 32, &lA[1][dofs]);
        load_lds16(gA1 + k0 + 32, &lA[1][dofs2]);
        load_lds16(gB0 + k0 + 32, &lB[1][dofs]);
        load_lds16(gB1 + k0 + 32, &lB[1][dofs2]);

        {
            bf16x8 af[4], bq[4];
            #pragma unroll
            for (int i = 0; i < 4; ++i)
                af[i] = *(const bf16x8*)&lA[0][fofsA + i * 16 * BK];
            #pragma unroll
            for (int j = 0; j < 4; ++j)
                bq[j] = *(const bf16x8*)&lB[0][fofsB + j * 16 * BK];
            #pragma unroll
            for (int i = 0; i < 4; ++i)
                #pragma unroll
                for (int j = 0; j < 4; ++j)
                    acc[i][j] = __builtin_amdgcn_mfma_f32_16x16x32_bf16(
                        af[i], bq[j], acc[i][j], 0, 0, 0);
        }

        __syncthreads();  // drain DMA(2kk+1) + buf0 reads
        if (kk < 15) {    // issue slab 2kk+2 -> buf0 (overlaps compute of 2kk+1)
            load_lds16(gA0 + k0 + 64, &lA[0][dofs]);
            load_lds16(gA1 + k0 + 64, &lA[0][dofs2]);
            load_lds16(gB0 + k0 + 64, &lB[0][dofs]);
            load_lds16(gB1 + k0 + 64, &lB[0][dofs2]);
        }

        {
            bf16x8 af[4], bq[4];
            #pragma unroll
            for (int i = 0; i < 4; ++i)
                af[i] = *(const bf16x8*)&lA[1][fofsA + i * 16 * BK];
            #pragma unroll
            for (int j = 0; j < 4; ++j)
                bq[j] = *(const bf16x8*)&lB[1][fofsB + j * 16 * BK];
            #pragma unroll
            for (int i = 0; i < 4; ++i)
                #pragma unroll
                for (int j = 0; j < 4; ++j)
                    acc[i][j] = __builtin_amdgcn_mfma_f32_16x16x32_bf16(
                        af[i], bq[j], acc[i][j], 0, 0, 0);
        }
    }

    // epilogue: C/D layout col=lane&15, row=quad*4+reg
    #pragma unroll
    for (int mi = 0; mi < 4; ++mi) {
        #pragma unroll
        for (int r = 0; r < 4; ++r) {
            int row = wm + mi * 16 + quad * 4 + r;
            if (row < rows) {
                int token = perm[tbase + row];
                float* op = out + token * OUT_FEAT + ntile * BN + wn;
                #pragma unroll
                for (int ni = 0; ni < 4; ++ni)
                    op[ni * 16 + l15] = acc[mi][ni][r];
            }
        }
    }
}

// ---- fallback (fused-convert gemm) if ws can't hold bf16 copies ----
#define FLDSW 20
__global__ __launch_bounds__(256, 4) void moe_gemm_fb(
    const float* __restrict__ inp,
    const float* __restrict__ weight,
    const int* __restrict__ perm,
    const int* __restrict__ seg,
    float* __restrict__ out) {

    const int bid = blockIdx.x;
    const int mtile = bid >> 7;
    const int e = (bid >> 4) & 7;
    const int ntile = bid & 15;

    const int base = seg[e];
    const int cnt = seg[e + 1] - base;
    if (mtile * 128 >= cnt) return;

    __shared__ unsigned int lA[128 * FLDSW];
    __shared__ unsigned int lB[64 * FLDSW];
    __shared__ int rowids[128];

    const int t = threadIdx.x;
    if (t < 128) {
        int r = mtile * 128 + t;
        rowids[t] = (r < cnt) ? perm[base + r] : -1;
    }
    __syncthreads();

    const int srow = t >> 1;
    const int scol = (t & 1) << 4;
    const int tokA = rowids[srow];
    const bool aval = (tokA >= 0);
    const float* aptr = inp + (aval ? tokA : 0) * IN_FEAT + scol;
    const int sdstA = srow * FLDSW + (scol >> 1);
    const int browB = t >> 2;
    const int bcol = (t & 3) << 3;
    const float* bptr = weight + e * (OUT_FEAT * IN_FEAT)
                        + (ntile * 64 + browB) * IN_FEAT + bcol;
    const int sdstB = browB * FLDSW + (bcol >> 1);

    const int wave = t >> 6;
    const int lane = t & 63;
    const int wm = (wave & 1) << 6;
    const int wn = (wave >> 1) << 5;
    const int l15 = lane & 15;
    const int quad = lane >> 4;

    f32x4 acc[4][2];
    #pragma unroll
    for (int i = 0; i < 4; ++i)
        #pragma unroll
        for (int j = 0; j < 2; ++j)
            acc[i][j] = (f32x4)0.0f;

    float4 ra[4], rb[2];
    {
        const float4* ap = (const float4*)aptr;
        const float4* bp = (const float4*)bptr;
        #pragma unroll
        for (int i = 0; i < 4; ++i) ra[i] = ap[i];
        #pragma unroll
        for (int i = 0; i < 2; ++i) rb[i] = bp[i];
    }

    for (int k0 = 0; k0 < IN_FEAT; k0 += 32) {
        unsigned int ua[8], ub[4];
        #pragma unroll
        for (int i = 0; i < 4; ++i) {
            ua[2 * i]     = pk2(ra[i].x, ra[i].y);
            ua[2 * i + 1] = pk2(ra[i].z, ra[i].w);
        }
        #pragma unroll
        for (int i = 0; i < 2; ++i) {
            ub[2 * i]     = pk2(rb[i].x, rb[i].y);
            ub[2 * i + 1] = pk2(rb[i].z, rb[i].w);
        }
        if (!aval) {
            #pragma unroll
            for (int i = 0; i < 8; ++i) ua[i] = 0u;
        }

        __syncthreads();
        *(uint4*)&lA[sdstA]     = make_uint4(ua[0], ua[1], ua[2], ua[3]);
        *(uint4*)&lA[sdstA + 4] = make_uint4(ua[4], ua[5], ua[6], ua[7]);
        *(uint4*)&lB[sdstB]     = make_uint4(ub[0], ub[1], ub[2], ub[3]);
        __syncthreads();

        if (k0 + 32 < IN_FEAT) {
            const float4* ap = (const float4*)(aptr + k0 + 32);
            const float4* bp = (const float4*)(bptr + k0 + 32);
            #pragma unroll
            for (int i = 0; i < 4; ++i) ra[i] = ap[i];
            #pragma unroll
            for (int i = 0; i < 2; ++i) rb[i] = bp[i];
        }

        bf16x8 af[4], bq[2];
        #pragma unroll
        for (int i = 0; i < 4; ++i)
            af[i] = *(const bf16x8*)&lA[(wm + i * 16 + l15) * FLDSW + (quad << 2)];
        #pragma unroll
        for (int j = 0; j < 2; ++j)
            bq[j] = *(const bf16x8*)&lB[(wn + j * 16 + l15) * FLDSW + (quad << 2)];

        #pragma unroll
        for (int i = 0; i < 4; ++i)
            #pragma unroll
            for (int j = 0; j < 2; ++j)
                acc[i][j] = __builtin_amdgcn_mfma_f32_16x16x32_bf16(
                    af[i], bq[j], acc[i][j], 0, 0, 0);
    }

    #pragma unroll
    for (int mi = 0; mi < 4; ++mi) {
        #pragma unroll
        for (int r = 0; r < 4; ++r) {
            int row = wm + mi * 16 + quad * 4 + r;
            int token = rowids[row];
            if (token >= 0) {
                float* op = out + token * OUT_FEAT + ntile * 64 + wn;
                #pragma unroll
                for (int ni = 0; ni < 2; ++ni)
                    op[ni * 16 + l15] = acc[mi][ni][r];
            }
        }
    }
}

extern "C" void kernel_launch(void* const* d_in, const int* in_sizes, int n_in,
                              void* d_out, int out_size, void* d_ws, size_t ws_size,
                              hipStream_t stream) {
    const float* inp = (const float*)d_in[0];
    const int* gate = (const int*)d_in[1];
    const float* weight = (const float*)d_in[2];
    float* out = (float*)d_out;

    int* perm = (int*)d_ws;           // 8192 ints
    int* seg = perm + N_TOKENS;       // 9 (pad 16)
    int* cnt = seg + 16;              // 8
    int* cur = cnt + 8;               // 8

    hipMemsetAsync(cnt, 0, 16 * sizeof(int), stream);
    moe_hist<<<N_TOKENS / 256, 256, 0, stream>>>(gate, cnt);
    moe_scan<<<1, 1, 0, stream>>>(cnt, seg, cur);
    moe_scatter<<<N_TOKENS / 256, 256, 0, stream>>>(gate, cur, perm);

    const size_t need = 65536 + 2ull * N_TOKENS * IN_FEAT * 2;  // 33.6 MB
    if (ws_size >= need) {
        unsigned int* A2 = (unsigned int*)((char*)d_ws + 65536);
        unsigned int* W2 = A2 + (N_TOKENS * IN_FEAT / 2);
        moe_prep<<<4096, 256, 0, stream>>>(inp, weight, perm, A2, W2);
        // bid = mtile*64 + ntile*8 + e ; 64 mtiles x 8 ntiles x 8 experts
        moe_gemm<<<4096, 256, 0, stream>>>((const unsigned short*)A2,
                                           (const unsigned short*)W2,
                                           perm, seg, out);
    } else {
        moe_gemm_fb<<<8192, 256, 0, stream>>>(inp, weight, perm, seg, out);
    }
}